// Round 1
// baseline (75.989 us; speedup 1.0000x reference)
//
#include <hip/hip_runtime.h>

// Log-signature depth 3, d=8, L=256.
// One wave (64 lanes) per batch element. Lane l = (i = l>>3, j = l&7).
// State per lane: s1 = S1[i], s2 = S2[i][j], s3[k] = S3[i][j][k] (k=0..7).
//
// Chen step with increment dx (using OLD state on the RHS):
//   S3[i][j][k] += (S2[i][j] + (0.5*S1[i] + (1/6)*dx[i])*dx[j]) * dx[k]
//   S2[i][j]    += (S1[i] + 0.5*dx[i]) * dx[j]
//   S1[i]       += dx[i]
// All step inputs are per-lane scalars except the dx row (broadcast from LDS).

#define WPB 4        // waves (= batch elems) per block
#define LEN 256
#define DCH 8
#define NSTEPS (LEN - 1)          // 255
#define OUTSTRIDE (DCH + DCH*DCH + DCH*DCH*DCH)  // 584

__global__ __launch_bounds__(256) void logsig_kernel(const float* __restrict__ x,
                                                     float* __restrict__ out) {
    __shared__ float dxbuf[WPB][2048];   // 255 used rows of 8 floats, padded
    __shared__ float s1buf[WPB][8];
    __shared__ float s2buf[WPB][64];

    const int tid  = threadIdx.x;
    const int w    = tid >> 6;
    const int lane = tid & 63;
    const int i    = lane >> 3;
    const int j    = lane & 7;
    const int b0   = blockIdx.x * WPB;

    // ---- Stage dx = x[t+1]-x[t] into LDS, block-cooperatively, float4 ----
    // Per batch: x has 512 float4; dx has 510 float4 (2040 floats).
    const float4* x4 = (const float4*)x;
    for (int n = tid; n < WPB * 510; n += 256) {
        int wb = n / 510;
        int f  = n - wb * 510;
        const float4* xb = x4 + (size_t)(b0 + wb) * 512;
        float4 a = xb[f];
        float4 c = xb[f + 2];
        float4 dv;
        dv.x = c.x - a.x; dv.y = c.y - a.y; dv.z = c.z - a.z; dv.w = c.w - a.w;
        *((float4*)&dxbuf[wb][f * 4]) = dv;
    }
    __syncthreads();

    // ---- Chen scan ----
    float s1 = 0.f, s2 = 0.f;
    float s3[8];
#pragma unroll
    for (int k = 0; k < 8; ++k) s3[k] = 0.f;

    const float* dxw = dxbuf[w];
    const float c6 = 1.f / 6.f;
#pragma unroll 5
    for (int t = 0; t < NSTEPS; ++t) {
        const float* row = dxw + t * 8;
        float4 r0 = *(const float4*)(row);      // ds_read_b128 (broadcast)
        float4 r1 = *(const float4*)(row + 4);  // ds_read_b128 (broadcast)
        float dxi = row[i];                     // ds_read_b32, 8-way bcast
        float dxj = row[j];                     // ds_read_b32, 8-way bcast

        float tt = fmaf(c6, dxi, 0.5f * s1);    // 0.5*S1[i] + dx[i]/6  (old s1)
        float w3 = fmaf(tt, dxj, s2);           // S2[i][j] + tt*dx[j]  (old s2)
        s3[0] = fmaf(w3, r0.x, s3[0]);
        s3[1] = fmaf(w3, r0.y, s3[1]);
        s3[2] = fmaf(w3, r0.z, s3[2]);
        s3[3] = fmaf(w3, r0.w, s3[3]);
        s3[4] = fmaf(w3, r1.x, s3[4]);
        s3[5] = fmaf(w3, r1.y, s3[5]);
        s3[6] = fmaf(w3, r1.z, s3[6]);
        s3[7] = fmaf(w3, r1.w, s3[7]);
        float u = fmaf(0.5f, dxi, s1);          // S1[i] + 0.5*dx[i] (old s1)
        s2 = fmaf(u, dxj, s2);
        s1 += dxi;
    }

    // ---- Epilogue: log map. Share S1 row and S2 across lanes via LDS ----
    if (j == 0) s1buf[w][i] = s1;
    s2buf[w][lane] = s2;      // s2buf[w][i*8+j]
    __syncthreads();

    float S1r[8], S2rj[8];
#pragma unroll
    for (int k = 0; k < 8; ++k) S1r[k] = s1buf[w][k];
#pragma unroll
    for (int k = 0; k < 8; ++k) S2rj[k] = s2buf[w][j * 8 + k];  // row j of S2
    float s1j = s1buf[w][j];

    const int b = b0 + w;
    float* ob = out + (size_t)b * OUTSTRIDE;

    // l1 = S1
    if (lane < 8) ob[lane] = s1buf[w][lane];
    // l2[i][j] = S2[i][j] - 0.5*S1[i]*S1[j]
    ob[8 + lane] = fmaf(-0.5f * s1, s1j, s2);
    // l3[i][j][k] = S3 - 0.5*(S1[i]*S2[j][k] + S2[i][j]*S1[k]) + (1/3)*S1[i]*S1[j]*S1[k]
    float c3 = (1.f / 3.f) * s1 * s1j;
    float l3[8];
#pragma unroll
    for (int k = 0; k < 8; ++k) {
        l3[k] = s3[k] - 0.5f * (s1 * S2rj[k] + s2 * S1r[k]) + c3 * S1r[k];
    }
    float4 o0 = make_float4(l3[0], l3[1], l3[2], l3[3]);
    float4 o1 = make_float4(l3[4], l3[5], l3[6], l3[7]);
    float* p3 = ob + 72 + lane * 8;
    *(float4*)(p3)     = o0;
    *(float4*)(p3 + 4) = o1;
}

extern "C" void kernel_launch(void* const* d_in, const int* in_sizes, int n_in,
                              void* d_out, int out_size, void* d_ws, size_t ws_size,
                              hipStream_t stream) {
    const float* x = (const float*)d_in[0];
    float* out = (float*)d_out;
    const int B = in_sizes[0] / (LEN * DCH);   // 2048
    const int blocks = B / WPB;                // 512
    hipLaunchKernelGGL(logsig_kernel, dim3(blocks), dim3(256), 0, stream, x, out);
}